// Round 11
// baseline (76.251 us; speedup 1.0000x reference)
//
#include <hip/hip_runtime.h>
#include <cfloat>

// ---------------------------------------------------------------------------
// VQ-VAE vector quantizer forward (MI355X / gfx950)
//   x        [32][64][64][64] f32   (B, D, H, W)
//   codebook [1024][64] f32
// out: x_q transposed back to [B,D,H,W] (8388608 f32)  +  loss scalar (1 f32)
//
// argmin_k ||x - c_k||^2  ==  argmax_k (x . c_k - ||c_k||^2/2)
// Sum_p SSE_p = Sum x^2 - 2 * Sum_p (best_score_p - 1),
//   score = dot + 1 - ||c||^2/2 (C-init), packed-u32 argmax (R5/R9-proven).
//
// R11 = R9 (42 us, proven) with ONE change: depth-3 B prefetch over a FULLY
// UNROLLED 16-iteration loop (all slot indices compile-time constant ->
// registers, not scratch; ~6 loads in flight -> counted vmcnt covers ~330cyc
// of L2 latency instead of depth-1's ~110). Grid stays 2048 (8 waves/SIMD,
// R10 proved TLP > per-wave ILP here). NO launch_bounds hint (R2/6/7/8:
// any min-waves hint caps arch-VGPRs at 64 and spills).
// Spill canary: FETCH~18MB / WRITE~33MB.
// ---------------------------------------------------------------------------

#define DD   64
#define HHWW 4096          // H*W
#define KC   1024
#define NBLK  2048         // one block per (b,h) row
#define NPOSD 8388608.0f   // N * D

typedef __bf16  bf16x8 __attribute__((ext_vector_type(8)));
typedef float   f32x4  __attribute__((ext_vector_type(4)));

__device__ __forceinline__ unsigned short bf16_bits(float f) {
  unsigned u = __float_as_uint(f);
  return (unsigned short)((u + 0x7FFFu + ((u >> 16) & 1u)) >> 16);  // RNE
}

__device__ __forceinline__ unsigned int umax2(unsigned int a, unsigned int b) {
  return a > b ? a : b;
}

// global->LDS direct copy, 16B per lane. ldst wave-uniform; HW adds lane*16.
__device__ __forceinline__ void gload_lds16(const void* gsrc, void* ldst) {
  __builtin_amdgcn_global_load_lds(
      (const __attribute__((address_space(1))) unsigned int*)gsrc,
      (__attribute__((address_space(3))) unsigned int*)ldst, 16, 0, 0);
}

// --- precompute: fragment-ordered bf16 codebook + replicated (1-||c||^2/2) --
__global__ __launch_bounds__(256) void vq_pre(
    const float* __restrict__ cb,          // [1024][64]
    unsigned short* __restrict__ cb_frag,  // [tile=64][kk=2][lane=64][e=8]
    float* __restrict__ hneg4)             // [1024][4] : 1-||c||^2/2, x4
{
  int k = blockIdx.x * 256 + threadIdx.x;
  if (k >= KC) return;
  float c[DD];
  float sum = 0.f;
#pragma unroll
  for (int d = 0; d < DD; ++d) { c[d] = cb[k * DD + d]; sum += c[d] * c[d]; }
  const float m = 1.0f - 0.5f * sum;
  hneg4[k * 4 + 0] = m; hneg4[k * 4 + 1] = m;
  hneg4[k * 4 + 2] = m; hneg4[k * 4 + 3] = m;
  int t = k >> 4, l15 = k & 15;
#pragma unroll
  for (int kk = 0; kk < 2; ++kk)
#pragma unroll
    for (int g = 0; g < 4; ++g)
#pragma unroll
      for (int e = 0; e < 8; ++e)
        cb_frag[(((t * 2 + kk) * 64) + (g * 16 + l15)) * 8 + e] =
            bf16_bits(c[kk * 32 + g * 8 + e]);
}

// --- main: fused distance-GEMM + argmin + loss partial + output write ------
__global__ __launch_bounds__(256) void vq_main(
    const float* __restrict__ x,
    const unsigned short* __restrict__ cb_frag,
    const float* __restrict__ hneg4,
    const float* __restrict__ cb,
    float* __restrict__ out,
    float* __restrict__ partials)
{
  __shared__ unsigned short xfrag[4096];   //  8 KB: row A-fragments (bf16)
  __shared__ f32x4          mh4_lds[KC];   // 16 KB: replicated C-init values
  __shared__ unsigned int   cand[4][64];   //  1 KB: per-wave winners
  __shared__ int            idx_lds[64];
  __shared__ float          xred[4];

  const int tid  = threadIdx.x;
  const int wv   = tid >> 6;
  const int lane = tid & 63;
  const int l15  = lane & 15;

  const int row = blockIdx.x;            // global (b,h) row, 0..2047
  const int b   = row >> 6;
  const int h   = row & 63;
  const float* xb = x + (size_t)b * DD * HHWW + h * 64;  // xb[d*4096 + w]

  // ---- stage hneg4 (16 KB) into LDS: 4 async rounds of 16 B/thread ----
#pragma unroll
  for (int i = 0; i < 4; ++i)
    gload_lds16((const char*)hneg4 + i * 4096 + (size_t)tid * 16,
                (char*)mh4_lds + i * 4096 + wv * 1024);

  // ---- cooperative coalesced x-stage -> bf16 fragment layout in LDS ----
  // float4 #m covers (d = m>>4, w = (m&15)*4 .. +3); 256B segments.
  float xacc = 0.f;
#pragma unroll
  for (int r4 = 0; r4 < 4; ++r4) {
    const int m  = tid + r4 * 256;
    const int d  = m >> 4;
    const int w4 = m & 15;
    const float4 v4 = *(const float4*)(xb + (size_t)d * HHWW + w4 * 4);
    const int kk = d >> 5, gg = (d >> 3) & 3, e = d & 7;
    const int pt = w4 >> 2;
    const int base = pt * 1024 + kk * 512 + gg * 128 + e;  // + l15*8
    const int lb = (w4 & 3) * 4;                           // l15 = lb + i
    xacc += v4.x * v4.x + v4.y * v4.y + v4.z * v4.z + v4.w * v4.w;
    xfrag[base + (lb + 0) * 8] = bf16_bits(v4.x);
    xfrag[base + (lb + 1) * 8] = bf16_bits(v4.y);
    xfrag[base + (lb + 2) * 8] = bf16_bits(v4.z);
    xfrag[base + (lb + 3) * 8] = bf16_bits(v4.w);
  }

  __syncthreads();                       // xfrag + mh4_lds ready

  // ---- A fragments from LDS (conflict-free ds_read_b128) ----
  // layout matches B: row i = lane&15, k = kk*32 + (lane>>4)*8 + e.
  bf16x8 afrag[4][2];
#pragma unroll
  for (int pt = 0; pt < 4; ++pt) {
    afrag[pt][0] = *(const bf16x8*)(&xfrag[pt * 1024 + lane * 8]);
    afrag[pt][1] = *(const bf16x8*)(&xfrag[pt * 1024 + 512 + lane * 8]);
  }

  // ---- this wave's 16 code tiles (codes wv*256 .. +255), depth-3 pf ----
  // best = (score_bits & ~1023) | (1023-code); score ~[0.95,1.05] > 0 so
  // bit pattern is order-preserving; ties prefer LOWER code (argmin).
  unsigned int best[4][4];
#pragma unroll
  for (int pt = 0; pt < 4; ++pt)
#pragma unroll
    for (int rr = 0; rr < 4; ++rr) best[pt][rr] = 0u;

  const unsigned int MASK = 0xFFFFFC00u;
  const int codec0 = 1023 - wv * 256 - l15;
  // cb_frag tile stride = 2048 B ([kk=2][lane=64][16B]); wave chunk = 16.
  const char*  bb  = (const char*)cb_frag + (size_t)wv * 16 * 2048 + (size_t)lane * 16;
  const f32x4* mhp = mh4_lds + wv * 256 + l15;   // + t*16 per tile

  // depth-3 rotating prefetch slots (fully unrolled loop -> static indices)
  bf16x8 pb0[3], pb1[3];
  f32x4  pmh[3];
#pragma unroll
  for (int s = 0; s < 3; ++s) {
    pb0[s] = *(const bf16x8*)(bb + s * 2048);
    pb1[s] = *(const bf16x8*)(bb + s * 2048 + 1024);
    pmh[s] = mhp[s * 16];
  }

#pragma unroll
  for (int t = 0; t < 16; ++t) {
    const int s = t % 3;                 // compile-time constant (full unroll)
    const bf16x8 b0 = pb0[s], b1 = pb1[s];
    const f32x4  mh = pmh[s];
    if (t + 3 < 16) {                    // prefetch tile t+3 into slot s
      pb0[s] = *(const bf16x8*)(bb + (t + 3) * 2048);
      pb1[s] = *(const bf16x8*)(bb + (t + 3) * 2048 + 1024);
      pmh[s] = mhp[(t + 3) * 16];
    }

    const unsigned int codec = (unsigned int)(codec0 - t * 16);

    f32x4 acc[4];
#pragma unroll
    for (int pt = 0; pt < 4; ++pt)      // C-init = mh4 (no movs)
      acc[pt] = __builtin_amdgcn_mfma_f32_16x16x32_bf16(afrag[pt][0], b0, mh, 0, 0, 0);
#pragma unroll
    for (int pt = 0; pt < 4; ++pt)
      acc[pt] = __builtin_amdgcn_mfma_f32_16x16x32_bf16(afrag[pt][1], b1, acc[pt], 0, 0, 0);

#pragma unroll
    for (int pt = 0; pt < 4; ++pt)
#pragma unroll
      for (int rr = 0; rr < 4; ++rr) {  // C/D: col=l15(code), row=g*4+rr(pos)
        const unsigned int p = (__float_as_uint(acc[pt][rr]) & MASK) | codec;
        best[pt][rr] = umax2(best[pt][rr], p);   // v_and_or + v_max
      }
  }

  // ---- cross-lane max over the 16 code columns (l15) ----
  const int g = lane >> 4;
#pragma unroll
  for (int pt = 0; pt < 4; ++pt)
#pragma unroll
    for (int rr = 0; rr < 4; ++rr) {
      unsigned int v = best[pt][rr];
#pragma unroll
      for (int m = 1; m < 16; m <<= 1) {
        unsigned int vo = __shfl_xor(v, m, 64);
        v = umax2(v, vo);
      }
      if (l15 == 0) cand[wv][pt * 16 + g * 4 + rr] = v;
    }

  // per-wave Sum x^2 reduce
#pragma unroll
  for (int m = 1; m < 64; m <<= 1) xacc += __shfl_xor(xacc, m, 64);
  if (lane == 0) xred[wv] = xacc;

  __syncthreads();

  // ---- wave 0: merge the 4 K-split candidates; loss partial ----
  if (tid < 64) {
    unsigned int v01 = umax2(cand[0][tid], cand[1][tid]);
    unsigned int v23 = umax2(cand[2][tid], cand[3][tid]);
    unsigned int v   = umax2(v01, v23);
    idx_lds[tid] = 1023 - (int)(v & 1023u);
    float vt1 = __uint_as_float(v & MASK) - 1.0f;   // dot - csq/2 (trunc)
#pragma unroll
    for (int m = 1; m < 64; m <<= 1) vt1 += __shfl_xor(vt1, m, 64);
    if (tid == 0)
      partials[blockIdx.x] =
          (xred[0] + xred[1] + xred[2] + xred[3]) - 2.0f * vt1;
  }

  __syncthreads();

  // ---- write quantized output; float4 gather from row-major cb ----
  const int myidx = idx_lds[lane];       // position w = lane
  const float4* crow = (const float4*)(cb + (size_t)myidx * DD) + wv * 4;
  const float4 c0 = crow[0], c1 = crow[1], c2 = crow[2], c3 = crow[3];
  float* ob = out + (size_t)b * DD * HHWW + h * 64 + lane;
  ob[(size_t)(wv * 16 +  0) * HHWW] = c0.x;
  ob[(size_t)(wv * 16 +  1) * HHWW] = c0.y;
  ob[(size_t)(wv * 16 +  2) * HHWW] = c0.z;
  ob[(size_t)(wv * 16 +  3) * HHWW] = c0.w;
  ob[(size_t)(wv * 16 +  4) * HHWW] = c1.x;
  ob[(size_t)(wv * 16 +  5) * HHWW] = c1.y;
  ob[(size_t)(wv * 16 +  6) * HHWW] = c1.z;
  ob[(size_t)(wv * 16 +  7) * HHWW] = c1.w;
  ob[(size_t)(wv * 16 +  8) * HHWW] = c2.x;
  ob[(size_t)(wv * 16 +  9) * HHWW] = c2.y;
  ob[(size_t)(wv * 16 + 10) * HHWW] = c2.z;
  ob[(size_t)(wv * 16 + 11) * HHWW] = c2.w;
  ob[(size_t)(wv * 16 + 12) * HHWW] = c3.x;
  ob[(size_t)(wv * 16 + 13) * HHWW] = c3.y;
  ob[(size_t)(wv * 16 + 14) * HHWW] = c3.z;
  ob[(size_t)(wv * 16 + 15) * HHWW] = c3.w;
}

// --- final loss reduce ------------------------------------------------------
__global__ __launch_bounds__(256) void vq_loss(
    const float* __restrict__ partials, float* __restrict__ loss_out)
{
  __shared__ float sred[4];
  int tid = threadIdx.x;
  float s = 0.f;
  for (int i = tid; i < NBLK; i += 256) s += partials[i];
#pragma unroll
  for (int m = 1; m < 64; m <<= 1) s += __shfl_xor(s, m, 64);
  if ((tid & 63) == 0) sred[tid >> 6] = s;
  __syncthreads();
  if (tid == 0)
    loss_out[0] = (sred[0] + sred[1] + sred[2] + sred[3]) * (1.25f / NPOSD);
}

extern "C" void kernel_launch(void* const* d_in, const int* in_sizes, int n_in,
                              void* d_out, int out_size, void* d_ws, size_t ws_size,
                              hipStream_t stream) {
  const float* x  = (const float*)d_in[0];
  const float* cb = (const float*)d_in[1];
  float* out      = (float*)d_out;
  float* loss_out = out + 8388608;

  char* ws = (char*)d_ws;
  unsigned short* cb_frag = (unsigned short*)(ws);      // 131072 B
  float* hneg4    = (float*)(ws + 131072);              //  16384 B
  float* partials = (float*)(ws + 147456);              //   8192 B

  vq_pre <<<4,    256, 0, stream>>>(cb, cb_frag, hneg4);
  vq_main<<<NBLK, 256, 0, stream>>>(x, cb_frag, hneg4, cb, out, partials);
  vq_loss<<<1,    256, 0, stream>>>(partials, loss_out);
}

// Round 12
// 46.748 us; speedup vs baseline: 1.6311x; 1.6311x over previous
//
#include <hip/hip_runtime.h>
#include <cfloat>

// ---------------------------------------------------------------------------
// VQ-VAE vector quantizer forward (MI355X / gfx950)
//   x        [32][64][64][64] f32   (B, D, H, W)
//   codebook [1024][64] f32
// out: x_q transposed back to [B,D,H,W] (8388608 f32)  +  loss scalar (1 f32)
//
// argmin_k ||x - c_k||^2  ==  argmax_k (x . c_k - ||c_k||^2/2)
// Sum_p SSE_p = Sum x^2 - 2 * Sum_p (best_score_p - 1),
//   score = dot + 1 - ||c||^2/2 (C-init), packed-u32 argmax (R5/R9-proven).
//
// R12 = R9 (42 us champion: block=row, 4 waves K-split, depth-1 L2 B-prefetch,
// VGPR 60, 8 waves/SIMD) + two occupancy/LDS fixes, NO structural change:
//  (1) mh4 C-init read DIRECTLY from global (L2-hot 16 KB table, depth-1
//      prefetched with the B tiles; R10-proven). Kills the 16 KB mh4_lds
//      staging -> LDS 26->9.5 KB -> all 8 blocks/CU co-resident (was 6).
//  (2) xfrag XOR-swizzle (l15 ^ pt on write AND read): staging writes were
//      ~16-way bank conflicts (1.8M cycles/dispatch); reads stay b128
//      conflict-free (XOR permutes within the 16-slot group).
// NO launch_bounds hint (R2/6/7/8: hint caps arch-VGPR at 64 -> spill).
// Canaries: FETCH~18MB, WRITE~33MB, VGPR~60.
// ---------------------------------------------------------------------------

#define DD   64
#define HHWW 4096          // H*W
#define KC   1024
#define NBLK  2048         // one block per (b,h) row
#define NPOSD 8388608.0f   // N * D

typedef __bf16  bf16x8 __attribute__((ext_vector_type(8)));
typedef float   f32x4  __attribute__((ext_vector_type(4)));

__device__ __forceinline__ unsigned short bf16_bits(float f) {
  unsigned u = __float_as_uint(f);
  return (unsigned short)((u + 0x7FFFu + ((u >> 16) & 1u)) >> 16);  // RNE
}

__device__ __forceinline__ unsigned int umax2(unsigned int a, unsigned int b) {
  return a > b ? a : b;
}

// --- precompute: fragment-ordered bf16 codebook + replicated (1-||c||^2/2) --
__global__ __launch_bounds__(256) void vq_pre(
    const float* __restrict__ cb,          // [1024][64]
    unsigned short* __restrict__ cb_frag,  // [tile=64][kk=2][lane=64][e=8]
    float* __restrict__ hneg4)             // [1024][4] : 1-||c||^2/2, x4
{
  int k = blockIdx.x * 256 + threadIdx.x;
  if (k >= KC) return;
  float c[DD];
  float sum = 0.f;
#pragma unroll
  for (int d = 0; d < DD; ++d) { c[d] = cb[k * DD + d]; sum += c[d] * c[d]; }
  const float m = 1.0f - 0.5f * sum;
  hneg4[k * 4 + 0] = m; hneg4[k * 4 + 1] = m;
  hneg4[k * 4 + 2] = m; hneg4[k * 4 + 3] = m;
  int t = k >> 4, l15 = k & 15;
#pragma unroll
  for (int kk = 0; kk < 2; ++kk)
#pragma unroll
    for (int g = 0; g < 4; ++g)
#pragma unroll
      for (int e = 0; e < 8; ++e)
        cb_frag[(((t * 2 + kk) * 64) + (g * 16 + l15)) * 8 + e] =
            bf16_bits(c[kk * 32 + g * 8 + e]);
}

// --- main: fused distance-GEMM + argmin + loss partial + output write ------
__global__ __launch_bounds__(256) void vq_main(
    const float* __restrict__ x,
    const unsigned short* __restrict__ cb_frag,
    const float* __restrict__ hneg4,
    const float* __restrict__ cb,
    float* __restrict__ out,
    float* __restrict__ partials)
{
  __shared__ unsigned short xfrag[4096];   //  8 KB: row A-fragments (bf16)
  __shared__ unsigned int   cand[4][64];   //  1 KB: per-wave winners
  __shared__ int            idx_lds[64];
  __shared__ float          xred[4];

  const int tid  = threadIdx.x;
  const int wv   = tid >> 6;
  const int lane = tid & 63;
  const int l15  = lane & 15;

  const int row = blockIdx.x;            // global (b,h) row, 0..2047
  const int b   = row >> 6;
  const int h   = row & 63;
  const float* xb = x + (size_t)b * DD * HHWW + h * 64;  // xb[d*4096 + w]

  // ---- cooperative coalesced x-stage -> bf16 fragment layout in LDS ----
  // float4 #m covers (d = m>>4, w = (m&15)*4 .. +3); 256B segments.
  // XOR-swizzle: l15-slot stored at (l15 ^ pt) to break staging-write bank
  // conflicts (write banks depended only on l15*4 -> ~16-way).
  float xacc = 0.f;
#pragma unroll
  for (int r4 = 0; r4 < 4; ++r4) {
    const int m  = tid + r4 * 256;
    const int d  = m >> 4;
    const int w4 = m & 15;
    const float4 v4 = *(const float4*)(xb + (size_t)d * HHWW + w4 * 4);
    const int kk = d >> 5, gg = (d >> 3) & 3, e = d & 7;
    const int pt = w4 >> 2;
    const int base = pt * 1024 + kk * 512 + gg * 128 + e;  // + (l15^pt)*8
    const int lb = (w4 & 3) * 4;                           // l15 = lb + i
    xacc += v4.x * v4.x + v4.y * v4.y + v4.z * v4.z + v4.w * v4.w;
    xfrag[base + ((lb + 0) ^ pt) * 8] = bf16_bits(v4.x);
    xfrag[base + ((lb + 1) ^ pt) * 8] = bf16_bits(v4.y);
    xfrag[base + ((lb + 2) ^ pt) * 8] = bf16_bits(v4.z);
    xfrag[base + ((lb + 3) ^ pt) * 8] = bf16_bits(v4.w);
  }

  __syncthreads();                       // xfrag ready

  // ---- A fragments from LDS (b128, XOR-matched -> still conflict-free) ----
  // layout matches B: row i = lane&15, k = kk*32 + (lane>>4)*8 + e.
  const int g = lane >> 4;
  bf16x8 afrag[4][2];
#pragma unroll
  for (int pt = 0; pt < 4; ++pt) {
    const int ls = g * 16 + (l15 ^ pt);
    afrag[pt][0] = *(const bf16x8*)(&xfrag[pt * 1024 + ls * 8]);
    afrag[pt][1] = *(const bf16x8*)(&xfrag[pt * 1024 + 512 + ls * 8]);
  }

  // ---- this wave's 16 code tiles (codes wv*256 .. +255), depth-1 pf ----
  // best = (score_bits & ~1023) | (1023-code); score ~[0.95,1.05] > 0 so
  // bit pattern is order-preserving; ties prefer LOWER code (argmin).
  unsigned int best[4][4];
#pragma unroll
  for (int pt = 0; pt < 4; ++pt)
#pragma unroll
    for (int rr = 0; rr < 4; ++rr) best[pt][rr] = 0u;

  const unsigned int MASK = 0xFFFFFC00u;
  const int codec0 = 1023 - wv * 256 - l15;
  // cb_frag tile stride = 2048 B ([kk=2][lane=64][16B]); wave chunk = 16.
  const char*  bb  = (const char*)cb_frag + (size_t)wv * 16 * 2048 + (size_t)lane * 16;
  // mh4: global, L2-hot 16 KB table (no LDS staging), depth-1 prefetched.
  const f32x4* mhp = (const f32x4*)hneg4 + wv * 256 + l15;   // + t*16 per tile

  bf16x8 nb0 = *(const bf16x8*)(bb);          // depth-1 prefetch (kk=0)
  bf16x8 nb1 = *(const bf16x8*)(bb + 1024);   // kk=1
  f32x4  nmh = mhp[0];

#pragma unroll 4
  for (int t = 0; t < 16; ++t) {
    const bf16x8 b0 = nb0, b1 = nb1;
    const f32x4  mh = nmh;
    const int tn = (t + 1) & 15;
    nb0 = *(const bf16x8*)(bb + tn * 2048);
    nb1 = *(const bf16x8*)(bb + tn * 2048 + 1024);
    nmh = mhp[tn * 16];

    const unsigned int codec = (unsigned int)(codec0 - t * 16);

    f32x4 acc[4];
#pragma unroll
    for (int pt = 0; pt < 4; ++pt)      // C-init = mh4 (no movs)
      acc[pt] = __builtin_amdgcn_mfma_f32_16x16x32_bf16(afrag[pt][0], b0, mh, 0, 0, 0);
#pragma unroll
    for (int pt = 0; pt < 4; ++pt)
      acc[pt] = __builtin_amdgcn_mfma_f32_16x16x32_bf16(afrag[pt][1], b1, acc[pt], 0, 0, 0);

#pragma unroll
    for (int pt = 0; pt < 4; ++pt)
#pragma unroll
      for (int rr = 0; rr < 4; ++rr) {  // C/D: col=l15(code), row=g*4+rr(pos)
        const unsigned int p = (__float_as_uint(acc[pt][rr]) & MASK) | codec;
        best[pt][rr] = umax2(best[pt][rr], p);   // v_and_or + v_max
      }
  }

  // ---- cross-lane max over the 16 code columns (l15) ----
#pragma unroll
  for (int pt = 0; pt < 4; ++pt)
#pragma unroll
    for (int rr = 0; rr < 4; ++rr) {
      unsigned int v = best[pt][rr];
#pragma unroll
      for (int m = 1; m < 16; m <<= 1) {
        unsigned int vo = __shfl_xor(v, m, 64);
        v = umax2(v, vo);
      }
      if (l15 == 0) cand[wv][pt * 16 + g * 4 + rr] = v;
    }

  // per-wave Sum x^2 reduce
#pragma unroll
  for (int m = 1; m < 64; m <<= 1) xacc += __shfl_xor(xacc, m, 64);
  if (lane == 0) xred[wv] = xacc;

  __syncthreads();

  // ---- wave 0: merge the 4 K-split candidates; loss partial ----
  if (tid < 64) {
    unsigned int v01 = umax2(cand[0][tid], cand[1][tid]);
    unsigned int v23 = umax2(cand[2][tid], cand[3][tid]);
    unsigned int v   = umax2(v01, v23);
    idx_lds[tid] = 1023 - (int)(v & 1023u);
    float vt1 = __uint_as_float(v & MASK) - 1.0f;   // dot - csq/2 (trunc)
#pragma unroll
    for (int m = 1; m < 64; m <<= 1) vt1 += __shfl_xor(vt1, m, 64);
    if (tid == 0)
      partials[blockIdx.x] =
          (xred[0] + xred[1] + xred[2] + xred[3]) - 2.0f * vt1;
  }

  __syncthreads();

  // ---- write quantized output; float4 gather from row-major cb ----
  const int myidx = idx_lds[lane];       // position w = lane
  const float4* crow = (const float4*)(cb + (size_t)myidx * DD) + wv * 4;
  const float4 c0 = crow[0], c1 = crow[1], c2 = crow[2], c3 = crow[3];
  float* ob = out + (size_t)b * DD * HHWW + h * 64 + lane;
  ob[(size_t)(wv * 16 +  0) * HHWW] = c0.x;
  ob[(size_t)(wv * 16 +  1) * HHWW] = c0.y;
  ob[(size_t)(wv * 16 +  2) * HHWW] = c0.z;
  ob[(size_t)(wv * 16 +  3) * HHWW] = c0.w;
  ob[(size_t)(wv * 16 +  4) * HHWW] = c1.x;
  ob[(size_t)(wv * 16 +  5) * HHWW] = c1.y;
  ob[(size_t)(wv * 16 +  6) * HHWW] = c1.z;
  ob[(size_t)(wv * 16 +  7) * HHWW] = c1.w;
  ob[(size_t)(wv * 16 +  8) * HHWW] = c2.x;
  ob[(size_t)(wv * 16 +  9) * HHWW] = c2.y;
  ob[(size_t)(wv * 16 + 10) * HHWW] = c2.z;
  ob[(size_t)(wv * 16 + 11) * HHWW] = c2.w;
  ob[(size_t)(wv * 16 + 12) * HHWW] = c3.x;
  ob[(size_t)(wv * 16 + 13) * HHWW] = c3.y;
  ob[(size_t)(wv * 16 + 14) * HHWW] = c3.z;
  ob[(size_t)(wv * 16 + 15) * HHWW] = c3.w;
}

// --- final loss reduce ------------------------------------------------------
__global__ __launch_bounds__(256) void vq_loss(
    const float* __restrict__ partials, float* __restrict__ loss_out)
{
  __shared__ float sred[4];
  int tid = threadIdx.x;
  float s = 0.f;
  for (int i = tid; i < NBLK; i += 256) s += partials[i];
#pragma unroll
  for (int m = 1; m < 64; m <<= 1) s += __shfl_xor(s, m, 64);
  if ((tid & 63) == 0) sred[tid >> 6] = s;
  __syncthreads();
  if (tid == 0)
    loss_out[0] = (sred[0] + sred[1] + sred[2] + sred[3]) * (1.25f / NPOSD);
}

extern "C" void kernel_launch(void* const* d_in, const int* in_sizes, int n_in,
                              void* d_out, int out_size, void* d_ws, size_t ws_size,
                              hipStream_t stream) {
  const float* x  = (const float*)d_in[0];
  const float* cb = (const float*)d_in[1];
  float* out      = (float*)d_out;
  float* loss_out = out + 8388608;

  char* ws = (char*)d_ws;
  unsigned short* cb_frag = (unsigned short*)(ws);      // 131072 B
  float* hneg4    = (float*)(ws + 131072);              //  16384 B
  float* partials = (float*)(ws + 147456);              //   8192 B

  vq_pre <<<4,    256, 0, stream>>>(cb, cb_frag, hneg4);
  vq_main<<<NBLK, 256, 0, stream>>>(x, cb_frag, hneg4, cb, out, partials);
  vq_loss<<<1,    256, 0, stream>>>(partials, loss_out);
}

// Round 13
// 45.772 us; speedup vs baseline: 1.6659x; 1.0213x over previous
//
#include <hip/hip_runtime.h>
#include <cfloat>

// ---------------------------------------------------------------------------
// VQ-VAE vector quantizer forward (MI355X / gfx950)
//   x        [32][64][64][64] f32   (B, D, H, W)
//   codebook [1024][64] f32
// out: x_q transposed back to [B,D,H,W] (8388608 f32)  +  loss scalar (1 f32)
//
// argmin_k ||x - c_k||^2  ==  argmax_k (x . c_k - ||c_k||^2/2)
// Sum_p SSE_p = Sum x^2 - 2 * Sum_p (best_score_p - 1),
//   score = dot + 1 - ||c||^2/2 (C-init), packed-u32 argmax (R5/R9-proven).
//
// R13 = R12 (40.8 us champion vq_main) + two zero-risk fixes:
//  (1) vq_pre rebuilt: 64 blocks, thread=(code,dquad), coalesced float4
//      reads + 16-lane shfl reduce + single 8B frag store (was 4 blocks
//      with 64 stride-256B scalar loads per thread, est 3-5 us -> ~1 us).
//  (2) vq_main XCD-aware row swizzle: row=(bid&7)*256+(bid>>3) (bijective)
//      -> each XCD's 32 CUs work a contiguous 256-row slab: 4MB x + 4MB out
//      fit its private L2; cb tables replicate per-XCD.
// vq_main body otherwise IDENTICAL to R12.
// Canaries: VGPR 64, FETCH<=18.6MB, WRITE~33MB, conflicts ~262K.
// ---------------------------------------------------------------------------

#define DD   64
#define HHWW 4096          // H*W
#define KC   1024
#define NBLK  2048         // one block per (b,h) row
#define NPOSD 8388608.0f   // N * D

typedef __bf16  bf16x8 __attribute__((ext_vector_type(8)));
typedef float   f32x4  __attribute__((ext_vector_type(4)));

__device__ __forceinline__ unsigned short bf16_bits(float f) {
  unsigned u = __float_as_uint(f);
  return (unsigned short)((u + 0x7FFFu + ((u >> 16) & 1u)) >> 16);  // RNE
}

__device__ __forceinline__ unsigned int umax2(unsigned int a, unsigned int b) {
  return a > b ? a : b;
}

// --- precompute: fragment-ordered bf16 codebook + replicated (1-||c||^2/2) --
// thread = (code k = tid/16 within grid, dim-quad q = tid&15).
// float4 load is coalesced (16 lanes cover one 64-f32 code row).
__global__ __launch_bounds__(256) void vq_pre(
    const float* __restrict__ cb,          // [1024][64]
    unsigned short* __restrict__ cb_frag,  // [tile=64][kk=2][lane=64][e=8]
    float* __restrict__ hneg4)             // [1024][4] : 1-||c||^2/2, x4
{
  const int gt = blockIdx.x * 256 + threadIdx.x;  // 0..16383
  const int k  = gt >> 4;                          // code 0..1023
  const int q  = gt & 15;                          // dim quad 0..15
  const float4 v = *(const float4*)(cb + (size_t)k * DD + q * 4);

  float s = v.x * v.x + v.y * v.y + v.z * v.z + v.w * v.w;
#pragma unroll
  for (int m = 1; m < 16; m <<= 1) s += __shfl_xor(s, m, 64);  // 16-group sum
  if (q == 0) {
    const float mval = 1.0f - 0.5f * s;
    float4 m4; m4.x = mval; m4.y = mval; m4.z = mval; m4.w = mval;
    *(float4*)(hneg4 + (size_t)k * 4) = m4;
  }

  // frag store: d = q*4+j -> kk=d>>5, g=(d>>3)&3, e=d&7. For a fixed q all
  // four j share kk,g and e = (q&1)*4 + j -> one contiguous 8B chunk.
  const int d0 = q * 4;
  const int kk = d0 >> 5, g = (d0 >> 3) & 3, e0 = d0 & 7;
  const int t = k >> 4, l15 = k & 15;
  unsigned short u0 = bf16_bits(v.x), u1 = bf16_bits(v.y);
  unsigned short u2 = bf16_bits(v.z), u3 = bf16_bits(v.w);
  uint2 wv2;
  wv2.x = (unsigned int)u0 | ((unsigned int)u1 << 16);
  wv2.y = (unsigned int)u2 | ((unsigned int)u3 << 16);
  *(uint2*)(&cb_frag[(((t * 2 + kk) * 64) + (g * 16 + l15)) * 8 + e0]) = wv2;
}

// --- main: fused distance-GEMM + argmin + loss partial + output write ------
__global__ __launch_bounds__(256) void vq_main(
    const float* __restrict__ x,
    const unsigned short* __restrict__ cb_frag,
    const float* __restrict__ hneg4,
    const float* __restrict__ cb,
    float* __restrict__ out,
    float* __restrict__ partials)
{
  __shared__ unsigned short xfrag[4096];   //  8 KB: row A-fragments (bf16)
  __shared__ unsigned int   cand[4][64];   //  1 KB: per-wave winners
  __shared__ int            idx_lds[64];
  __shared__ float          xred[4];

  const int tid  = threadIdx.x;
  const int wv   = tid >> 6;
  const int lane = tid & 63;
  const int l15  = lane & 15;

  // XCD-aware swizzle: XCD n (bid%8) owns contiguous rows n*256..n*256+255
  // -> 4MB x-slab + 4MB out-slab fit the XCD's private L2. Bijective.
  const int row = ((blockIdx.x & 7) << 8) + (blockIdx.x >> 3);
  const int b   = row >> 6;
  const int h   = row & 63;
  const float* xb = x + (size_t)b * DD * HHWW + h * 64;  // xb[d*4096 + w]

  // ---- cooperative coalesced x-stage -> bf16 fragment layout in LDS ----
  // float4 #m covers (d = m>>4, w = (m&15)*4 .. +3); 256B segments.
  // XOR-swizzle: l15-slot stored at (l15 ^ pt) to break staging-write bank
  // conflicts; reads use the same XOR (both-sides rule).
  float xacc = 0.f;
#pragma unroll
  for (int r4 = 0; r4 < 4; ++r4) {
    const int m  = tid + r4 * 256;
    const int d  = m >> 4;
    const int w4 = m & 15;
    const float4 v4 = *(const float4*)(xb + (size_t)d * HHWW + w4 * 4);
    const int kk = d >> 5, gg = (d >> 3) & 3, e = d & 7;
    const int pt = w4 >> 2;
    const int base = pt * 1024 + kk * 512 + gg * 128 + e;  // + (l15^pt)*8
    const int lb = (w4 & 3) * 4;                           // l15 = lb + i
    xacc += v4.x * v4.x + v4.y * v4.y + v4.z * v4.z + v4.w * v4.w;
    xfrag[base + ((lb + 0) ^ pt) * 8] = bf16_bits(v4.x);
    xfrag[base + ((lb + 1) ^ pt) * 8] = bf16_bits(v4.y);
    xfrag[base + ((lb + 2) ^ pt) * 8] = bf16_bits(v4.z);
    xfrag[base + ((lb + 3) ^ pt) * 8] = bf16_bits(v4.w);
  }

  __syncthreads();                       // xfrag ready

  // ---- A fragments from LDS (b128, XOR-matched -> conflict-free) ----
  // layout matches B: row i = lane&15, k = kk*32 + (lane>>4)*8 + e.
  const int g = lane >> 4;
  bf16x8 afrag[4][2];
#pragma unroll
  for (int pt = 0; pt < 4; ++pt) {
    const int ls = g * 16 + (l15 ^ pt);
    afrag[pt][0] = *(const bf16x8*)(&xfrag[pt * 1024 + ls * 8]);
    afrag[pt][1] = *(const bf16x8*)(&xfrag[pt * 1024 + 512 + ls * 8]);
  }

  // ---- this wave's 16 code tiles (codes wv*256 .. +255), depth-1 pf ----
  // best = (score_bits & ~1023) | (1023-code); score ~[0.95,1.05] > 0 so
  // bit pattern is order-preserving; ties prefer LOWER code (argmin).
  unsigned int best[4][4];
#pragma unroll
  for (int pt = 0; pt < 4; ++pt)
#pragma unroll
    for (int rr = 0; rr < 4; ++rr) best[pt][rr] = 0u;

  const unsigned int MASK = 0xFFFFFC00u;
  const int codec0 = 1023 - wv * 256 - l15;
  // cb_frag tile stride = 2048 B ([kk=2][lane=64][16B]); wave chunk = 16.
  const char*  bb  = (const char*)cb_frag + (size_t)wv * 16 * 2048 + (size_t)lane * 16;
  // mh4: global, L2-hot 16 KB table (no LDS staging), depth-1 prefetched.
  const f32x4* mhp = (const f32x4*)hneg4 + wv * 256 + l15;   // + t*16 per tile

  bf16x8 nb0 = *(const bf16x8*)(bb);          // depth-1 prefetch (kk=0)
  bf16x8 nb1 = *(const bf16x8*)(bb + 1024);   // kk=1
  f32x4  nmh = mhp[0];

#pragma unroll 4
  for (int t = 0; t < 16; ++t) {
    const bf16x8 b0 = nb0, b1 = nb1;
    const f32x4  mh = nmh;
    const int tn = (t + 1) & 15;
    nb0 = *(const bf16x8*)(bb + tn * 2048);
    nb1 = *(const bf16x8*)(bb + tn * 2048 + 1024);
    nmh = mhp[tn * 16];

    const unsigned int codec = (unsigned int)(codec0 - t * 16);

    f32x4 acc[4];
#pragma unroll
    for (int pt = 0; pt < 4; ++pt)      // C-init = mh4 (no movs)
      acc[pt] = __builtin_amdgcn_mfma_f32_16x16x32_bf16(afrag[pt][0], b0, mh, 0, 0, 0);
#pragma unroll
    for (int pt = 0; pt < 4; ++pt)
      acc[pt] = __builtin_amdgcn_mfma_f32_16x16x32_bf16(afrag[pt][1], b1, acc[pt], 0, 0, 0);

#pragma unroll
    for (int pt = 0; pt < 4; ++pt)
#pragma unroll
      for (int rr = 0; rr < 4; ++rr) {  // C/D: col=l15(code), row=g*4+rr(pos)
        const unsigned int p = (__float_as_uint(acc[pt][rr]) & MASK) | codec;
        best[pt][rr] = umax2(best[pt][rr], p);   // v_and_or + v_max
      }
  }

  // ---- cross-lane max over the 16 code columns (l15) ----
#pragma unroll
  for (int pt = 0; pt < 4; ++pt)
#pragma unroll
    for (int rr = 0; rr < 4; ++rr) {
      unsigned int v = best[pt][rr];
#pragma unroll
      for (int m = 1; m < 16; m <<= 1) {
        unsigned int vo = __shfl_xor(v, m, 64);
        v = umax2(v, vo);
      }
      if (l15 == 0) cand[wv][pt * 16 + g * 4 + rr] = v;
    }

  // per-wave Sum x^2 reduce
#pragma unroll
  for (int m = 1; m < 64; m <<= 1) xacc += __shfl_xor(xacc, m, 64);
  if (lane == 0) xred[wv] = xacc;

  __syncthreads();

  // ---- wave 0: merge the 4 K-split candidates; loss partial ----
  if (tid < 64) {
    unsigned int v01 = umax2(cand[0][tid], cand[1][tid]);
    unsigned int v23 = umax2(cand[2][tid], cand[3][tid]);
    unsigned int v   = umax2(v01, v23);
    idx_lds[tid] = 1023 - (int)(v & 1023u);
    float vt1 = __uint_as_float(v & MASK) - 1.0f;   // dot - csq/2 (trunc)
#pragma unroll
    for (int m = 1; m < 64; m <<= 1) vt1 += __shfl_xor(vt1, m, 64);
    if (tid == 0)
      partials[blockIdx.x] =
          (xred[0] + xred[1] + xred[2] + xred[3]) - 2.0f * vt1;
  }

  __syncthreads();

  // ---- write quantized output; float4 gather from row-major cb ----
  const int myidx = idx_lds[lane];       // position w = lane
  const float4* crow = (const float4*)(cb + (size_t)myidx * DD) + wv * 4;
  const float4 c0 = crow[0], c1 = crow[1], c2 = crow[2], c3 = crow[3];
  float* ob = out + (size_t)b * DD * HHWW + h * 64 + lane;
  ob[(size_t)(wv * 16 +  0) * HHWW] = c0.x;
  ob[(size_t)(wv * 16 +  1) * HHWW] = c0.y;
  ob[(size_t)(wv * 16 +  2) * HHWW] = c0.z;
  ob[(size_t)(wv * 16 +  3) * HHWW] = c0.w;
  ob[(size_t)(wv * 16 +  4) * HHWW] = c1.x;
  ob[(size_t)(wv * 16 +  5) * HHWW] = c1.y;
  ob[(size_t)(wv * 16 +  6) * HHWW] = c1.z;
  ob[(size_t)(wv * 16 +  7) * HHWW] = c1.w;
  ob[(size_t)(wv * 16 +  8) * HHWW] = c2.x;
  ob[(size_t)(wv * 16 +  9) * HHWW] = c2.y;
  ob[(size_t)(wv * 16 + 10) * HHWW] = c2.z;
  ob[(size_t)(wv * 16 + 11) * HHWW] = c2.w;
  ob[(size_t)(wv * 16 + 12) * HHWW] = c3.x;
  ob[(size_t)(wv * 16 + 13) * HHWW] = c3.y;
  ob[(size_t)(wv * 16 + 14) * HHWW] = c3.z;
  ob[(size_t)(wv * 16 + 15) * HHWW] = c3.w;
}

// --- final loss reduce ------------------------------------------------------
__global__ __launch_bounds__(256) void vq_loss(
    const float* __restrict__ partials, float* __restrict__ loss_out)
{
  __shared__ float sred[4];
  int tid = threadIdx.x;
  float s = 0.f;
  for (int i = tid; i < NBLK; i += 256) s += partials[i];
#pragma unroll
  for (int m = 1; m < 64; m <<= 1) s += __shfl_xor(s, m, 64);
  if ((tid & 63) == 0) sred[tid >> 6] = s;
  __syncthreads();
  if (tid == 0)
    loss_out[0] = (sred[0] + sred[1] + sred[2] + sred[3]) * (1.25f / NPOSD);
}

extern "C" void kernel_launch(void* const* d_in, const int* in_sizes, int n_in,
                              void* d_out, int out_size, void* d_ws, size_t ws_size,
                              hipStream_t stream) {
  const float* x  = (const float*)d_in[0];
  const float* cb = (const float*)d_in[1];
  float* out      = (float*)d_out;
  float* loss_out = out + 8388608;

  char* ws = (char*)d_ws;
  unsigned short* cb_frag = (unsigned short*)(ws);      // 131072 B
  float* hneg4    = (float*)(ws + 131072);              //  16384 B
  float* partials = (float*)(ws + 147456);              //   8192 B

  vq_pre <<<64,   256, 0, stream>>>(cb, cb_frag, hneg4);
  vq_main<<<NBLK, 256, 0, stream>>>(x, cb_frag, hneg4, cb, out, partials);
  vq_loss<<<1,    256, 0, stream>>>(partials, loss_out);
}